// Round 2
// baseline (1195.853 us; speedup 1.0000x reference)
//
#include <hip/hip_runtime.h>
#include <hip/hip_bf16.h>
#include <math.h>

#define HW 16384      // 128*128
#define BATCH 4
#define KIDS 20

using short8 = __attribute__((ext_vector_type(8))) short;  // 8 bf16 = 16B
using f32x4  = __attribute__((ext_vector_type(4))) float;

__device__ __forceinline__ unsigned short bfbits(float f) {
  __hip_bfloat16 h = __float2bfloat16(f);
  return *(unsigned short*)&h;
}

// async global -> LDS, 16B per lane, wave-uniform LDS base + lane*16
__device__ __forceinline__ void gload_lds16(const void* g, void* l) {
  __builtin_amdgcn_global_load_lds(
      (const __attribute__((address_space(1))) void*)g,
      (__attribute__((address_space(3))) void*)l, 16, 0, 0);
}

__global__ __launch_bounds__(256) void zero_k(float* __restrict__ p, int n) {
  int i = blockIdx.x*256 + threadIdx.x;
  if (i < n) p[i] = 0.f;
}

// ---- x: fp32 NCHW [4][512][128][128] -> bf16 NHWC [4][16384][512] ----------
__global__ __launch_bounds__(256) void x_to_nhwc_k(const float* __restrict__ in,
                                                   __hip_bfloat16* __restrict__ out)
{
  __shared__ float tile[32][65];
  int t = blockIdx.x;
  const int pxt = t & 255; t >>= 8;
  const int ct  = t & 15;  t >>= 4;
  const int b   = t;
  const int tid = threadIdx.x;
  #pragma unroll
  for (int it = 0; it < 8; ++it) {
    int idx = tid + it*256;
    int px_l = idx & 63, c_l = idx >> 6;
    tile[c_l][px_l] = in[((size_t)(b*512 + ct*32 + c_l))*HW + pxt*64 + px_l];
  }
  __syncthreads();
  #pragma unroll
  for (int it = 0; it < 4; ++it) {
    int idx = tid + it*256;
    int c2 = idx & 15, px_l = idx >> 4;
    unsigned u = ((unsigned)bfbits(tile[c2*2+1][px_l]) << 16) | bfbits(tile[c2*2][px_l]);
    *(unsigned*)(out + ((size_t)(b*HW + pxt*64 + px_l))*512 + ct*32 + c2*2) = u;
  }
}

// ---- weights: fp32 [Co][Ci][3][3] -> bf16 [9][Co][Ci] ----------------------
template<int Co, int Ci>
__global__ __launch_bounds__(256) void pack_w_k(const float* __restrict__ w,
                                                __hip_bfloat16* __restrict__ out)
{
  const int i = blockIdx.x*256 + threadIdx.x;
  const int ci = i & (Ci-1);
  const int r  = i >> __builtin_ctz(Ci);
  const int co = r & (Co-1);
  const int t  = r >> __builtin_ctz(Co);
  out[i] = __float2bfloat16(w[((size_t)co*Ci + ci)*9 + t]);
}

// ---- implicit-GEMM conv3x3 via MFMA + fused GN partial stats ---------------
// block: ROWS output rows x (MT*16) co, 4 waves. wave = 1 row x (128/NW) px.
// LDS: (ROWS+2) rows x 130 px x 32 ci, px-stride 32 shorts (NO pad).
// Staging is global_load_lds direct (wave-uniform base + lane*16 matches the
// row-interior layout); OOB halo rows are zeroed ONCE and never overwritten.
// Weights are double-buffered in registers one tap ahead to hide L2 latency.
// Tiles sized so 4 blocks/CU are resident (occupancy = latency hiding).
template<int Ci, int Co, int ROWS, int CPG, int MT>
__global__ __launch_bounds__(256, 4) void conv_mfma_k(
    const __hip_bfloat16* __restrict__ xin,  // NHWC bf16 [4][16384][Ci]
    const __hip_bfloat16* __restrict__ wpk,  // [9][Co][Ci] bf16
    const float* __restrict__ bias,
    float* __restrict__ out,                 // NHWC fp32 [4][16384][Co]
    float* __restrict__ partS, float* __restrict__ partSS)
{
  constexpr int NW = 4 / ROWS;         // waves along px
  constexpr int WN = 128 / NW;
  constexpr int NT = WN / 16;          // px tiles per wave
  constexpr int SR = ROWS + 2;
  constexpr int RG = 128 / ROWS;
  constexpr int NG = (MT*16) / CPG;    // groups covered per block
  constexpr int LPW = SR*2;            // global_load_lds per wave per chunk
  __shared__ __align__(16) short bl[SR*130*32];

  const int b  = blockIdx.x / RG;
  const int r0 = (blockIdx.x % RG) * ROWS;
  const int co0 = blockIdx.y * (MT*16);
  const int tid = threadIdx.x;
  const int wave = tid >> 6, lane = tid & 63;
  const int row_w = wave % ROWS;
  const int wn    = wave / ROWS;
  const int y = r0 + row_w;
  const int lr = lane & 15, q = lane >> 4;

  // zero the px-pad slots (px index 0 and 129) once
  if (tid < SR*2*4) {
    int q16 = tid & 3, sp = tid >> 2;
    int r = sp >> 1, side = sp & 1;
    short8 z = {0,0,0,0,0,0,0,0};
    *(short8*)(bl + (r*130 + (side ? 129 : 0))*32 + q16*8) = z;
  }
  // zero OOB halo rows once; staging skips them so they stay zero all chunks
  {
    short8 z = {0,0,0,0,0,0,0,0};
    if (r0 == 0) {
      short8* base = (short8*)bl;                      // row 0
      for (int i = tid; i < 130*32/8; i += 256) base[i] = z;
    }
    if (r0 == 128-ROWS) {
      short8* base = (short8*)(bl + (SR-1)*130*32);    // row SR-1
      for (int i = tid; i < 130*32/8; i += 256) base[i] = z;
    }
  }

  f32x4 acc[MT][NT] = {};
  const size_t in_base = (size_t)b * HW * Ci;
  const int px_s = lane >> 2, q16_s = lane & 3;        // staging lane split

  for (int ci0 = 0; ci0 < Ci; ci0 += 32) {
    __syncthreads();   // previous chunk's ds_reads done before overwrite
    // stage SR rows x 128 px x 32 ci, direct to LDS (interior rows only)
    #pragma unroll
    for (int it = 0; it < LPW; ++it) {
      const int gi = wave*LPW + it;
      const int r  = gi >> 3;
      const int p0 = (gi & 7) * 16;
      const int yy = r0 + r - 1;
      if ((unsigned)yy < 128u) {
        const __hip_bfloat16* src = xin + in_base
            + (size_t)(yy*128 + p0 + px_s)*Ci + ci0 + q16_s*8;
        gload_lds16(src, bl + (r*130 + p0 + 1)*32);
      }
    }
    // issue tap-0 weights now: latency hides under the stage drain
    short8 wreg[2][MT];
    #pragma unroll
    for (int mt = 0; mt < MT; ++mt)
      wreg[0][mt] = *(const short8*)(wpk +
          ((size_t)(0*Co + co0 + mt*16 + lr))*Ci + ci0 + q*8);
    __syncthreads();   // drains vmcnt(0): LDS tile + tap-0 weights ready

    #pragma unroll
    for (int t = 0; t < 9; ++t) {
      const int cur = t & 1, nxt = cur ^ 1;
      // prefetch next tap's weights (L2) under this tap's MFMAs
      if (t < 8) {
        #pragma unroll
        for (int mt = 0; mt < MT; ++mt)
          wreg[nxt][mt] = *(const short8*)(wpk +
              ((size_t)((t+1)*Co + co0 + mt*16 + lr))*Ci + ci0 + q*8);
      }
      const int dy = t / 3, dx = t % 3;
      short8 bf[NT];
      #pragma unroll
      for (int nt = 0; nt < NT; ++nt) {
        int px = wn*WN + nt*16 + lr;
        bf[nt] = *(const short8*)(bl + ((row_w + dy)*130 + px + dx)*32 + q*8);
      }
      #pragma unroll
      for (int mt = 0; mt < MT; ++mt)
        #pragma unroll
        for (int nt = 0; nt < NT; ++nt)
          acc[mt][nt] = __builtin_amdgcn_mfma_f32_16x16x32_bf16(
              wreg[cur][mt], bf[nt], acc[mt][nt], 0, 0, 0);
    }
  }

  // epilogue: +bias, store, and accumulate GN partial stats
  float sg[NG] = {}, ssg[NG] = {};
  #pragma unroll
  for (int mt = 0; mt < MT; ++mt) {
    const int g = (mt*16) / CPG;
    #pragma unroll
    for (int nt = 0; nt < NT; ++nt) {
      int px = wn*WN + nt*16 + lr;
      int co = co0 + mt*16 + q*4;
      const float4 bv = *(const float4*)(bias + co);
      f32x4 v = acc[mt][nt];
      v[0] += bv.x; v[1] += bv.y; v[2] += bv.z; v[3] += bv.w;
      sg[g]  += v[0] + v[1] + v[2] + v[3];
      ssg[g] += v[0]*v[0] + v[1]*v[1] + v[2]*v[2] + v[3]*v[3];
      *(f32x4*)(out + ((size_t)(b*HW + y*128 + px))*Co + co) = v;
    }
  }
  const int bgbase = b*(Co/CPG) + co0/CPG;
  #pragma unroll
  for (int g = 0; g < NG; ++g) {
    float s = sg[g], ss = ssg[g];
    #pragma unroll
    for (int off = 32; off; off >>= 1) {
      s  += __shfl_xor(s, off);
      ss += __shfl_xor(ss, off);
    }
    if (lane == 0) {
      atomicAdd(&partS[bgbase + g], s);
      atomicAdd(&partSS[bgbase + g], ss);
    }
  }
}

// ---- GN finalize: mean / rsqrt(var) from atomic partials -------------------
__global__ void gn_final_k(const float* __restrict__ partS,
                           const float* __restrict__ partSS,
                           float* __restrict__ mv, int nbg, float inv_n)
{
  const int i = threadIdx.x;
  if (i < nbg) {
    float s = partS[i], ss = partSS[i];
    float mean = s*inv_n, var = ss*inv_n - mean*mean;
    mv[2*i] = mean; mv[2*i+1] = rsqrtf(var + 1e-5f);
  }
}

// ---- GN apply: normalize+affine+ReLU; emit bf16 (or fp32) NHWC -------------
template<int C, int CPG, bool BF16OUT>
__global__ __launch_bounds__(256) void gn_apply_k(const float* __restrict__ in,
    const float* __restrict__ mv, const float* __restrict__ gw,
    const float* __restrict__ gb, void* __restrict__ outp)
{
  constexpr int C4 = C/4;
  constexpr int G = C/CPG;
  const int i = blockIdx.x*256 + threadIdx.x;
  const int c4 = i & (C4-1);
  const int pxb = i >> __builtin_ctz(C4);
  const int b = pxb >> 14;
  const int c = c4*4;
  const int bg = b*G + c/CPG;
  const float mean = mv[2*bg], inv = mv[2*bg+1];
  float4 v = *((const float4*)in + i);
  const float4 w4 = *(const float4*)(gw + c);
  const float4 b4 = *(const float4*)(gb + c);
  float r0 = fmaxf((v.x-mean)*inv*w4.x + b4.x, 0.f);
  float r1 = fmaxf((v.y-mean)*inv*w4.y + b4.y, 0.f);
  float r2 = fmaxf((v.z-mean)*inv*w4.z + b4.z, 0.f);
  float r3 = fmaxf((v.w-mean)*inv*w4.w + b4.w, 0.f);
  if (BF16OUT) {
    uint2 o;
    o.x = ((unsigned)bfbits(r1) << 16) | bfbits(r0);
    o.y = ((unsigned)bfbits(r3) << 16) | bfbits(r2);
    *(uint2*)((__hip_bfloat16*)outp + (size_t)i*4) = o;
  } else {
    *((float4*)outp + i) = make_float4(r0,r1,r2,r3);
  }
}

// ---- pooling ---------------------------------------------------------------
__global__ __launch_bounds__(256) void pool_counts_k(
    const int* __restrict__ masks, float* __restrict__ counts)
{
  __shared__ int hist[KIDS];
  const int b = blockIdx.x;
  if (threadIdx.x < KIDS) hist[threadIdx.x] = 0;
  __syncthreads();
  for (int p = threadIdx.x; p < HW; p += 256) {
    const int m = masks[b*HW + p];
    if (m > 0) atomicAdd(&hist[m-1], 1);
  }
  __syncthreads();
  if (threadIdx.x < KIDS) counts[b*KIDS + threadIdx.x] = (float)hist[threadIdx.x];
}

__global__ __launch_bounds__(256) void pool_sums_k(const float* __restrict__ h3,
    const int* __restrict__ masks, float* __restrict__ sums)
{
  __shared__ float acc[KIDS*64];
  const int b = blockIdx.x >> 5, chunk = blockIdx.x & 31;
  const int tid = threadIdx.x;
  for (int j = tid; j < KIDS*64; j += 256) acc[j] = 0.f;
  __syncthreads();
  const int ch = tid & 63, pi = tid >> 6;
  const int p0 = chunk*512;
  for (int p = p0 + pi; p < p0 + 512; p += 4) {
    int m = masks[b*HW + p];
    if (m > 0) atomicAdd(&acc[(m-1)*64 + ch], h3[((size_t)(b*HW + p))*64 + ch]);
  }
  __syncthreads();
  for (int j = tid; j < KIDS*64; j += 256) atomicAdd(&sums[b*KIDS*64 + j], acc[j]);
}

// ---- heads: one wave per (b,k) ---------------------------------------------
__global__ __launch_bounds__(64) void heads_k(
    const float* __restrict__ sums, const float* __restrict__ counts,
    const float* __restrict__ wb, const float* __restrict__ bb,
    const float* __restrict__ wc, const float* __restrict__ bc,
    float* __restrict__ out)
{
  const int bk = blockIdx.x;
  const int c = threadIdx.x;
  const float pooled = sums[bk*64 + c] / (counts[bk] + 1e-6f);
  #pragma unroll
  for (int o = 0; o < 7; ++o) {
    float t = pooled * wb[o*64 + c];
    for (int off = 32; off > 0; off >>= 1) t += __shfl_down(t, off);
    if (c == 0) out[bk*7 + o] = t + bb[o];
  }
  float t = pooled * wc[c];
  for (int off = 32; off > 0; off >>= 1) t += __shfl_down(t, off);
  if (c == 0) out[BATCH*KIDS*7 + bk] = 1.f / (1.f + expf(-(t + bc[0])));
}

extern "C" void kernel_launch(void* const* d_in, const int* in_sizes, int n_in,
                              void* d_out, int out_size, void* d_ws, size_t ws_size,
                              hipStream_t stream)
{
  const float* x     = (const float*)d_in[0];
  const int*   masks = (const int*)  d_in[1];
  const float* w1 = (const float*)d_in[2];
  const float* b1 = (const float*)d_in[3];
  const float* g1w= (const float*)d_in[4];
  const float* g1b= (const float*)d_in[5];
  const float* w2 = (const float*)d_in[6];
  const float* b2 = (const float*)d_in[7];
  const float* g2w= (const float*)d_in[8];
  const float* g2b= (const float*)d_in[9];
  const float* w3 = (const float*)d_in[10];
  const float* b3 = (const float*)d_in[11];
  const float* g3w= (const float*)d_in[12];
  const float* g3b= (const float*)d_in[13];
  const float* wb = (const float*)d_in[14];
  const float* bb = (const float*)d_in[15];
  const float* wc = (const float*)d_in[16];
  const float* bc = (const float*)d_in[17];
  float* out = (float*)d_out;

  char* ws = (char*)d_ws;
  // region A [0,64MB): xb during conv1; then h1b(32) + h2b(16) + h3(16)
  __hip_bfloat16* xb  = (__hip_bfloat16*)ws;
  __hip_bfloat16* h1b = (__hip_bfloat16*)ws;
  __hip_bfloat16* h2b = (__hip_bfloat16*)(ws + (size_t)(32<<20));
  float*          h3  = (float*)         (ws + (size_t)(48<<20));
  // region B [64,128MB): c1(64); then c2(32)+c3(16)
  float* c1 = (float*)(ws + (size_t)(64<<20));
  float* c2 = c1;
  float* c3 = (float*)(ws + (size_t)(96<<20));
  // packed weights + small buffers at 128MB
  __hip_bfloat16* wp1 = (__hip_bfloat16*)(ws + (size_t)(128<<20));
  __hip_bfloat16* wp2 = wp1 + 9*256*512;
  __hip_bfloat16* wp3 = wp2 + 9*128*256;
  char* tail = (char*)(wp3 + 9*64*128);
  float* mv     = (float*)tail;                 // 64 floats
  float* partS  = mv + 64;                      // 64 (layer offs 0/32/48)
  float* partSS = partS + 64;                   // 64
  float* sums   = partSS + 64;                  // 5120
  float* counts = sums + 5120;                  // 80

  // zero atomic accumulators (partS, partSS, sums are contiguous: 5248 floats)
  zero_k<<<21, 256, 0, stream>>>(partS, 64 + 64 + 5120);

  x_to_nhwc_k<<<16384, 256, 0, stream>>>(x, xb);
  pack_w_k<256,512><<<4608, 256, 0, stream>>>(w1, wp1);
  pack_w_k<128,256><<<1152, 256, 0, stream>>>(w2, wp2);
  pack_w_k< 64,128><<< 288, 256, 0, stream>>>(w3, wp3);

  // layer 1: 512 -> 256, GN(8 groups, cpg 32). ROWS=2 -> 1024 blocks, 4/CU
  conv_mfma_k<512,256,2,32,4><<<dim3(256,4), 256, 0, stream>>>(
      xb, wp1, b1, c1, partS, partSS);
  gn_final_k<<<1, 64, 0, stream>>>(partS, partSS, mv, 32, 1.f/(32.f*HW));
  gn_apply_k<256,32,true><<<16384, 256, 0, stream>>>(c1, mv, g1w, g1b, h1b);

  // layer 2: 256 -> 128, GN(4 groups, cpg 32). ROWS=1 -> 1024 blocks, 4/CU
  conv_mfma_k<256,128,1,32,4><<<dim3(512,2), 256, 0, stream>>>(
      h1b, wp2, b2, c2, partS + 32, partSS + 32);
  gn_final_k<<<1, 64, 0, stream>>>(partS + 32, partSS + 32, mv, 16, 1.f/(32.f*HW));
  gn_apply_k<128,32,true><<<8192, 256, 0, stream>>>(c2, mv, g2w, g2b, h2b);

  // layer 3: 128 -> 64, GN(4 groups, cpg 16); fp32 out. ROWS=1, MT=2 -> 1024 blocks
  conv_mfma_k<128,64,1,16,2><<<dim3(512,2), 256, 0, stream>>>(
      h2b, wp3, b3, c3, partS + 48, partSS + 48);
  gn_final_k<<<1, 64, 0, stream>>>(partS + 48, partSS + 48, mv, 16, 1.f/(16.f*HW));
  gn_apply_k<64,16,false><<<4096, 256, 0, stream>>>(c3, mv, g3w, g3b, h3);

  // pooling + heads
  pool_counts_k<<<BATCH, 256, 0, stream>>>(masks, counts);
  pool_sums_k<<<BATCH*32, 256, 0, stream>>>(h3, masks, sums);
  heads_k<<<BATCH*KIDS, 64, 0, stream>>>(sums, counts, wb, bb, wc, bc, out);
}

// Round 3
// 798.060 us; speedup vs baseline: 1.4985x; 1.4985x over previous
//
#include <hip/hip_runtime.h>
#include <hip/hip_bf16.h>
#include <math.h>

#define HW 16384      // 128*128
#define BATCH 4
#define KIDS 20

using short8 = __attribute__((ext_vector_type(8))) short;  // 8 bf16 = 16B
using f32x4  = __attribute__((ext_vector_type(4))) float;

__device__ __forceinline__ unsigned short bfbits(float f) {
  __hip_bfloat16 h = __float2bfloat16(f);
  return *(unsigned short*)&h;
}

// async global -> LDS, 16B per lane, wave-uniform LDS base + lane*16
__device__ __forceinline__ void gload_lds16(const void* g, void* l) {
  __builtin_amdgcn_global_load_lds(
      (const __attribute__((address_space(1))) void*)g,
      (__attribute__((address_space(3))) void*)l, 16, 0, 0);
}

__global__ __launch_bounds__(256) void zero_k(float* __restrict__ p, int n) {
  int i = blockIdx.x*256 + threadIdx.x;
  if (i < n) p[i] = 0.f;
}

// ---- x: fp32 NCHW [4][512][128][128] -> bf16 NHWC [4][16384][512] ----------
__global__ __launch_bounds__(256) void x_to_nhwc_k(const float* __restrict__ in,
                                                   __hip_bfloat16* __restrict__ out)
{
  __shared__ float tile[32][65];
  int t = blockIdx.x;
  const int pxt = t & 255; t >>= 8;
  const int ct  = t & 15;  t >>= 4;
  const int b   = t;
  const int tid = threadIdx.x;
  #pragma unroll
  for (int it = 0; it < 8; ++it) {
    int idx = tid + it*256;
    int px_l = idx & 63, c_l = idx >> 6;
    tile[c_l][px_l] = in[((size_t)(b*512 + ct*32 + c_l))*HW + pxt*64 + px_l];
  }
  __syncthreads();
  #pragma unroll
  for (int it = 0; it < 4; ++it) {
    int idx = tid + it*256;
    int c2 = idx & 15, px_l = idx >> 4;
    unsigned u = ((unsigned)bfbits(tile[c2*2+1][px_l]) << 16) | bfbits(tile[c2*2][px_l]);
    *(unsigned*)(out + ((size_t)(b*HW + pxt*64 + px_l))*512 + ct*32 + c2*2) = u;
  }
}

// ---- weights: fp32 [Co][Ci][3][3] -> bf16 [9][Co][Ci] ----------------------
template<int Co, int Ci>
__global__ __launch_bounds__(256) void pack_w_k(const float* __restrict__ w,
                                                __hip_bfloat16* __restrict__ out)
{
  const int i = blockIdx.x*256 + threadIdx.x;
  const int ci = i & (Ci-1);
  const int r  = i >> __builtin_ctz(Ci);
  const int co = r & (Co-1);
  const int t  = r >> __builtin_ctz(Co);
  out[i] = __float2bfloat16(w[((size_t)co*Ci + ci)*9 + t]);
}

// ---- implicit-GEMM conv3x3 via MFMA + fused GN partial stats ---------------
// 512-thread block = 8 waves: ROWS rows x PXW px-splits x 2 co-halves.
// Block covers ROWS rows x 128 px x (2*MT*16) co -> grid = 256 = 1 block/CU.
// LDS: DOUBLE-buffered (ROWS+2) x 130 x 32ci tile; staging for chunk c+1 is
// issued (global_load_lds direct) BEFORE computing chunk c, so the stage
// latency hides under ~10k cycles of MFMA; the single __syncthreads per chunk
// drains it for free. OOB halo rows zeroed once (both buffers), never written.
template<int Ci, int Co, int ROWS, int CPG, int MT>
__global__ __launch_bounds__(512, 2) void conv_mfma_k(
    const __hip_bfloat16* __restrict__ xin,  // NHWC bf16 [4][16384][Ci]
    const __hip_bfloat16* __restrict__ wpk,  // [9][Co][Ci] bf16
    const float* __restrict__ bias,
    float* __restrict__ out,                 // NHWC fp32 [4][16384][Co]
    float* __restrict__ partS, float* __restrict__ partSS)
{
  constexpr int PXW = (8/ROWS)/2;      // px-split waves (conv1:1, conv2/3:2)
  constexpr int WN  = 128/PXW;
  constexpr int NT  = WN/16;           // px tiles per wave
  constexpr int SR  = ROWS + 2;
  constexpr int RG  = 128 / ROWS;
  constexpr int NC  = Ci / 32;
  constexpr int NGW = (MT*16)/CPG;     // GN groups per wave's co range
  constexpr int BSZ = SR*130*32;       // shorts per LDS buffer
  __shared__ __align__(16) short bl[2*BSZ];

  const int b  = blockIdx.x / RG;
  const int r0 = (blockIdx.x % RG) * ROWS;
  const int co0 = blockIdx.y * (2*MT*16);
  const int tid = threadIdx.x;
  const int wave = tid >> 6, lane = tid & 63;
  const int row_w = wave % ROWS;
  const int rem   = wave / ROWS;
  const int pw    = rem % PXW;
  const int coh   = rem / PXW;
  const int co_w  = co0 + coh*MT*16;
  const int y = r0 + row_w;
  const int lr = lane & 15, q = lane >> 4;
  const int px_s = lane >> 2, q16_s = lane & 3;   // staging lane split

  // zero the px-pad slots (px index 0 and 129) once, BOTH buffers
  if (tid < 2*SR*2*4) {
    int u = tid; int q16 = u & 3; u >>= 2;
    int side = u & 1; u >>= 1;
    int r = u % SR, buf = u / SR;
    short8 z = {0,0,0,0,0,0,0,0};
    *(short8*)(bl + buf*BSZ + (r*130 + (side ? 129 : 0))*32 + q16*8) = z;
  }
  // zero OOB halo rows once (both buffers); staging skips them
  if (r0 == 0) {
    short8 z = {0,0,0,0,0,0,0,0};
    for (int i = tid; i < 2*520; i += 512) {
      int buf = i / 520, j = i % 520;
      *((short8*)(bl + buf*BSZ) + j) = z;                    // row 0
    }
  }
  if (r0 == 128-ROWS) {
    short8 z = {0,0,0,0,0,0,0,0};
    for (int i = tid; i < 2*520; i += 512) {
      int buf = i / 520, j = i % 520;
      *((short8*)(bl + buf*BSZ + (SR-1)*130*32) + j) = z;    // row SR-1
    }
  }

  const size_t in_base = (size_t)b * HW * Ci;
  // stage SR rows x 128 px x 32 ci into buffer `buf` (interior rows only)
  auto stage = [&](int buf, int ci0) {
    #pragma unroll
    for (int it = 0; it < SR; ++it) {
      int gi = wave*SR + it;
      int r = gi >> 3, seg = gi & 7;
      int yy = r0 + r - 1;
      if ((unsigned)yy < 128u) {
        const __hip_bfloat16* src = xin + in_base
            + (size_t)(yy*128 + seg*16 + px_s)*Ci + ci0 + q16_s*8;
        gload_lds16(src, bl + buf*BSZ + (r*130 + seg*16 + 1)*32);
      }
    }
  };

  f32x4 acc[MT][NT] = {};
  stage(0, 0);
  __syncthreads();                      // buf0 ready
  int cur = 0;
  for (int c = 0; c < NC; ++c) {
    const int ci0 = c*32;
    if (c+1 < NC) stage(cur^1, ci0 + 32);   // issue-early: flies under compute
    const short* blc = bl + cur*BSZ;
    short8 wreg[2][MT];
    #pragma unroll
    for (int mt = 0; mt < MT; ++mt)
      wreg[0][mt] = *(const short8*)(wpk +
          ((size_t)(0*Co + co_w + mt*16 + lr))*Ci + ci0 + q*8);
    #pragma unroll
    for (int t = 0; t < 9; ++t) {
      const int cb = t & 1, nb = cb ^ 1;
      if (t < 8) {                      // prefetch next tap's weights
        #pragma unroll
        for (int mt = 0; mt < MT; ++mt)
          wreg[nb][mt] = *(const short8*)(wpk +
              ((size_t)((t+1)*Co + co_w + mt*16 + lr))*Ci + ci0 + q*8);
      }
      const int dy = t / 3, dx = t % 3;
      short8 bf[NT];
      #pragma unroll
      for (int nt = 0; nt < NT; ++nt) {
        int px = pw*WN + nt*16 + lr;
        bf[nt] = *(const short8*)(blc + ((row_w + dy)*130 + px + dx)*32 + q*8);
      }
      #pragma unroll
      for (int mt = 0; mt < MT; ++mt)
        #pragma unroll
        for (int nt = 0; nt < NT; ++nt)
          acc[mt][nt] = __builtin_amdgcn_mfma_f32_16x16x32_bf16(
              wreg[cb][mt], bf[nt], acc[mt][nt], 0, 0, 0);
    }
    __syncthreads();                    // drains next-chunk stage (already flown)
    cur ^= 1;
  }

  // epilogue: +bias, store, and accumulate GN partial stats
  float sg[NGW] = {}, ssg[NGW] = {};
  #pragma unroll
  for (int mt = 0; mt < MT; ++mt) {
    const int g = (mt*16) / CPG;
    #pragma unroll
    for (int nt = 0; nt < NT; ++nt) {
      int px = pw*WN + nt*16 + lr;
      int co = co_w + mt*16 + q*4;
      const float4 bv = *(const float4*)(bias + co);
      f32x4 v = acc[mt][nt];
      v[0] += bv.x; v[1] += bv.y; v[2] += bv.z; v[3] += bv.w;
      sg[g]  += v[0] + v[1] + v[2] + v[3];
      ssg[g] += v[0]*v[0] + v[1]*v[1] + v[2]*v[2] + v[3]*v[3];
      *(f32x4*)(out + ((size_t)(b*HW + y*128 + px))*Co + co) = v;
    }
  }
  const int bgbase = b*(Co/CPG) + co_w/CPG;
  #pragma unroll
  for (int g = 0; g < NGW; ++g) {
    float s = sg[g], ss = ssg[g];
    #pragma unroll
    for (int off = 32; off; off >>= 1) {
      s  += __shfl_xor(s, off);
      ss += __shfl_xor(ss, off);
    }
    if (lane == 0) {
      atomicAdd(&partS[bgbase + g], s);
      atomicAdd(&partSS[bgbase + g], ss);
    }
  }
}

// ---- GN finalize: mean / rsqrt(var) from atomic partials -------------------
__global__ void gn_final_k(const float* __restrict__ partS,
                           const float* __restrict__ partSS,
                           float* __restrict__ mv, int nbg, float inv_n)
{
  const int i = threadIdx.x;
  if (i < nbg) {
    float s = partS[i], ss = partSS[i];
    float mean = s*inv_n, var = ss*inv_n - mean*mean;
    mv[2*i] = mean; mv[2*i+1] = rsqrtf(var + 1e-5f);
  }
}

// ---- GN apply: normalize+affine+ReLU; emit bf16 (or fp32) NHWC -------------
template<int C, int CPG, bool BF16OUT>
__global__ __launch_bounds__(256) void gn_apply_k(const float* __restrict__ in,
    const float* __restrict__ mv, const float* __restrict__ gw,
    const float* __restrict__ gb, void* __restrict__ outp)
{
  constexpr int C4 = C/4;
  constexpr int G = C/CPG;
  const int i = blockIdx.x*256 + threadIdx.x;
  const int c4 = i & (C4-1);
  const int pxb = i >> __builtin_ctz(C4);
  const int b = pxb >> 14;
  const int c = c4*4;
  const int bg = b*G + c/CPG;
  const float mean = mv[2*bg], inv = mv[2*bg+1];
  float4 v = *((const float4*)in + i);
  const float4 w4 = *(const float4*)(gw + c);
  const float4 b4 = *(const float4*)(gb + c);
  float r0 = fmaxf((v.x-mean)*inv*w4.x + b4.x, 0.f);
  float r1 = fmaxf((v.y-mean)*inv*w4.y + b4.y, 0.f);
  float r2 = fmaxf((v.z-mean)*inv*w4.z + b4.z, 0.f);
  float r3 = fmaxf((v.w-mean)*inv*w4.w + b4.w, 0.f);
  if (BF16OUT) {
    uint2 o;
    o.x = ((unsigned)bfbits(r1) << 16) | bfbits(r0);
    o.y = ((unsigned)bfbits(r3) << 16) | bfbits(r2);
    *(uint2*)((__hip_bfloat16*)outp + (size_t)i*4) = o;
  } else {
    *((float4*)outp + i) = make_float4(r0,r1,r2,r3);
  }
}

// ---- pooling ---------------------------------------------------------------
__global__ __launch_bounds__(256) void pool_counts_k(
    const int* __restrict__ masks, float* __restrict__ counts)
{
  __shared__ int hist[KIDS];
  const int b = blockIdx.x;
  if (threadIdx.x < KIDS) hist[threadIdx.x] = 0;
  __syncthreads();
  for (int p = threadIdx.x; p < HW; p += 256) {
    const int m = masks[b*HW + p];
    if (m > 0) atomicAdd(&hist[m-1], 1);
  }
  __syncthreads();
  if (threadIdx.x < KIDS) counts[b*KIDS + threadIdx.x] = (float)hist[threadIdx.x];
}

__global__ __launch_bounds__(256) void pool_sums_k(const float* __restrict__ h3,
    const int* __restrict__ masks, float* __restrict__ sums)
{
  __shared__ float acc[KIDS*64];
  const int b = blockIdx.x >> 5, chunk = blockIdx.x & 31;
  const int tid = threadIdx.x;
  for (int j = tid; j < KIDS*64; j += 256) acc[j] = 0.f;
  __syncthreads();
  const int ch = tid & 63, pi = tid >> 6;
  const int p0 = chunk*512;
  for (int p = p0 + pi; p < p0 + 512; p += 4) {
    int m = masks[b*HW + p];
    if (m > 0) atomicAdd(&acc[(m-1)*64 + ch], h3[((size_t)(b*HW + p))*64 + ch]);
  }
  __syncthreads();
  for (int j = tid; j < KIDS*64; j += 256) atomicAdd(&sums[b*KIDS*64 + j], acc[j]);
}

// ---- heads: one wave per (b,k) ---------------------------------------------
__global__ __launch_bounds__(64) void heads_k(
    const float* __restrict__ sums, const float* __restrict__ counts,
    const float* __restrict__ wb, const float* __restrict__ bb,
    const float* __restrict__ wc, const float* __restrict__ bc,
    float* __restrict__ out)
{
  const int bk = blockIdx.x;
  const int c = threadIdx.x;
  const float pooled = sums[bk*64 + c] / (counts[bk] + 1e-6f);
  #pragma unroll
  for (int o = 0; o < 7; ++o) {
    float t = pooled * wb[o*64 + c];
    for (int off = 32; off > 0; off >>= 1) t += __shfl_down(t, off);
    if (c == 0) out[bk*7 + o] = t + bb[o];
  }
  float t = pooled * wc[c];
  for (int off = 32; off > 0; off >>= 1) t += __shfl_down(t, off);
  if (c == 0) out[BATCH*KIDS*7 + bk] = 1.f / (1.f + expf(-(t + bc[0])));
}

extern "C" void kernel_launch(void* const* d_in, const int* in_sizes, int n_in,
                              void* d_out, int out_size, void* d_ws, size_t ws_size,
                              hipStream_t stream)
{
  const float* x     = (const float*)d_in[0];
  const int*   masks = (const int*)  d_in[1];
  const float* w1 = (const float*)d_in[2];
  const float* b1 = (const float*)d_in[3];
  const float* g1w= (const float*)d_in[4];
  const float* g1b= (const float*)d_in[5];
  const float* w2 = (const float*)d_in[6];
  const float* b2 = (const float*)d_in[7];
  const float* g2w= (const float*)d_in[8];
  const float* g2b= (const float*)d_in[9];
  const float* w3 = (const float*)d_in[10];
  const float* b3 = (const float*)d_in[11];
  const float* g3w= (const float*)d_in[12];
  const float* g3b= (const float*)d_in[13];
  const float* wb = (const float*)d_in[14];
  const float* bb = (const float*)d_in[15];
  const float* wc = (const float*)d_in[16];
  const float* bc = (const float*)d_in[17];
  float* out = (float*)d_out;

  char* ws = (char*)d_ws;
  // region A [0,64MB): xb during conv1; then h1b(32) + h2b(16) + h3(16)
  __hip_bfloat16* xb  = (__hip_bfloat16*)ws;
  __hip_bfloat16* h1b = (__hip_bfloat16*)ws;
  __hip_bfloat16* h2b = (__hip_bfloat16*)(ws + (size_t)(32<<20));
  float*          h3  = (float*)         (ws + (size_t)(48<<20));
  // region B [64,128MB): c1(64); then c2(32)+c3(16)
  float* c1 = (float*)(ws + (size_t)(64<<20));
  float* c2 = c1;
  float* c3 = (float*)(ws + (size_t)(96<<20));
  // packed weights + small buffers at 128MB
  __hip_bfloat16* wp1 = (__hip_bfloat16*)(ws + (size_t)(128<<20));
  __hip_bfloat16* wp2 = wp1 + 9*256*512;
  __hip_bfloat16* wp3 = wp2 + 9*128*256;
  char* tail = (char*)(wp3 + 9*64*128);
  float* mv     = (float*)tail;                 // 64 floats
  float* partS  = mv + 64;                      // 64 (layer offs 0/32/48)
  float* partSS = partS + 64;                   // 64
  float* sums   = partSS + 64;                  // 5120
  float* counts = sums + 5120;                  // 80

  // zero atomic accumulators (partS, partSS, sums are contiguous: 5248 floats)
  zero_k<<<21, 256, 0, stream>>>(partS, 64 + 64 + 5120);

  x_to_nhwc_k<<<16384, 256, 0, stream>>>(x, xb);
  pack_w_k<256,512><<<4608, 256, 0, stream>>>(w1, wp1);
  pack_w_k<128,256><<<1152, 256, 0, stream>>>(w2, wp2);
  pack_w_k< 64,128><<< 288, 256, 0, stream>>>(w3, wp3);

  // layer 1: 512 -> 256, GN(8 groups, cpg 32). ROWS=4, 128co/block, 256 blocks
  conv_mfma_k<512,256,4,32,4><<<dim3(128,2), 512, 0, stream>>>(
      xb, wp1, b1, c1, partS, partSS);
  gn_final_k<<<1, 64, 0, stream>>>(partS, partSS, mv, 32, 1.f/(32.f*HW));
  gn_apply_k<256,32,true><<<16384, 256, 0, stream>>>(c1, mv, g1w, g1b, h1b);

  // layer 2: 256 -> 128, GN(4 groups, cpg 32). ROWS=2, 128co/block, 256 blocks
  conv_mfma_k<256,128,2,32,4><<<dim3(256,1), 512, 0, stream>>>(
      h1b, wp2, b2, c2, partS + 32, partSS + 32);
  gn_final_k<<<1, 64, 0, stream>>>(partS + 32, partSS + 32, mv, 16, 1.f/(32.f*HW));
  gn_apply_k<128,32,true><<<8192, 256, 0, stream>>>(c2, mv, g2w, g2b, h2b);

  // layer 3: 128 -> 64, GN(4 groups, cpg 16); fp32 out. ROWS=2, 64co, 256 blocks
  conv_mfma_k<128,64,2,16,2><<<dim3(256,1), 512, 0, stream>>>(
      h2b, wp3, b3, c3, partS + 48, partSS + 48);
  gn_final_k<<<1, 64, 0, stream>>>(partS + 48, partSS + 48, mv, 16, 1.f/(16.f*HW));
  gn_apply_k<64,16,false><<<4096, 256, 0, stream>>>(c3, mv, g3w, g3b, h3);

  // pooling + heads
  pool_counts_k<<<BATCH, 256, 0, stream>>>(masks, counts);
  pool_sums_k<<<BATCH*32, 256, 0, stream>>>(h3, masks, sums);
  heads_k<<<BATCH*KIDS, 64, 0, stream>>>(sums, counts, wb, bb, wc, bc, out);
}

// Round 4
// 705.964 us; speedup vs baseline: 1.6939x; 1.1305x over previous
//
#include <hip/hip_runtime.h>
#include <hip/hip_bf16.h>
#include <math.h>

#define HW 16384      // 128*128
#define BATCH 4
#define KIDS 20

using short8 = __attribute__((ext_vector_type(8))) short;  // 8 bf16 = 16B
using f32x4  = __attribute__((ext_vector_type(4))) float;

__device__ __forceinline__ unsigned short bfbits(float f) {
  __hip_bfloat16 h = __float2bfloat16(f);
  return *(unsigned short*)&h;
}

// async global -> LDS, 16B per lane, wave-uniform LDS base + lane*16
__device__ __forceinline__ void gload_lds16(const void* g, void* l) {
  __builtin_amdgcn_global_load_lds(
      (const __attribute__((address_space(1))) void*)g,
      (__attribute__((address_space(3))) void*)l, 16, 0, 0);
}

__global__ __launch_bounds__(256) void zero_k(float* __restrict__ p, int n) {
  int i = blockIdx.x*256 + threadIdx.x;
  if (i < n) p[i] = 0.f;
}

// ---- x: fp32 NCHW [4][512][128][128] -> bf16 NHWC [4][16384][512] ----------
__global__ __launch_bounds__(256) void x_to_nhwc_k(const float* __restrict__ in,
                                                   __hip_bfloat16* __restrict__ out)
{
  __shared__ float tile[32][65];
  int t = blockIdx.x;
  const int pxt = t & 255; t >>= 8;
  const int ct  = t & 15;  t >>= 4;
  const int b   = t;
  const int tid = threadIdx.x;
  #pragma unroll
  for (int it = 0; it < 8; ++it) {
    int idx = tid + it*256;
    int px_l = idx & 63, c_l = idx >> 6;
    tile[c_l][px_l] = in[((size_t)(b*512 + ct*32 + c_l))*HW + pxt*64 + px_l];
  }
  __syncthreads();
  #pragma unroll
  for (int it = 0; it < 4; ++it) {
    int idx = tid + it*256;
    int c2 = idx & 15, px_l = idx >> 4;
    unsigned u = ((unsigned)bfbits(tile[c2*2+1][px_l]) << 16) | bfbits(tile[c2*2][px_l]);
    *(unsigned*)(out + ((size_t)(b*HW + pxt*64 + px_l))*512 + ct*32 + c2*2) = u;
  }
}

// ---- weights: fp32 [Co][Ci][3][3] -> bf16 [9][Co][Ci] ----------------------
template<int Co, int Ci>
__global__ __launch_bounds__(256) void pack_w_k(const float* __restrict__ w,
                                                __hip_bfloat16* __restrict__ out)
{
  const int i = blockIdx.x*256 + threadIdx.x;
  const int ci = i & (Ci-1);
  const int r  = i >> __builtin_ctz(Ci);
  const int co = r & (Co-1);
  const int t  = r >> __builtin_ctz(Co);
  out[i] = __float2bfloat16(w[((size_t)co*Ci + ci)*9 + t]);
}

// ---- implicit-GEMM conv3x3 via MFMA + fused GN partial stats ---------------
// 512-thread block = 8 waves: 2 rows x 2 px-halves x 2 co-halves.
// Block covers 2 rows x 128 px x WCO co (WCO = 2*MT*16).
// LDS: input tile DOUBLE-buffered (4 x 130 x 32ci, no px pad conflicts) +
// weight tile for the current ci-chunk (9 taps x WCO x 32ci), single-buffered.
// Per chunk: issue weight gload_lds (9/wave), then next-chunk input gload_lds
// (4/wave), then counted `s_waitcnt vmcnt(4)` (weights + previous input done;
// next input keeps flying under compute) + raw s_barrier. Compute phase is
// PURE LDS+MFMA (no global ops -> no in-order vmcnt stalls inside the taps).
template<int Ci, int Co, int CPG, int MT>
__global__ __launch_bounds__(512, 2) void conv_mfma_k(
    const __hip_bfloat16* __restrict__ xin,  // NHWC bf16 [4][16384][Ci]
    const __hip_bfloat16* __restrict__ wpk,  // [9][Co][Ci] bf16
    const float* __restrict__ bias,
    float* __restrict__ out,                 // NHWC fp32 [4][16384][Co]
    float* __restrict__ partS, float* __restrict__ partSS)
{
  constexpr int ROWS = 2, NT = 4, SR = 4, RG = 64;
  constexpr int WCO = 2*MT*16;         // co per block
  constexpr int NC  = Ci/32;           // ci chunks
  constexpr int NGW = (MT*16)/CPG;     // GN groups per wave's co range
  constexpr int IB  = SR*130*32;       // shorts per input buffer
  constexpr int UW  = 9*WCO/16;        // weight 1KB-units per chunk
  __shared__ __align__(16) short lds[2*IB + 9*WCO*32];
  short* const wlds = lds + 2*IB;

  const int b  = blockIdx.x / RG;
  const int r0 = (blockIdx.x % RG) * ROWS;
  const int co0 = blockIdx.y * WCO;
  const int tid = threadIdx.x;
  const int wave = tid >> 6, lane = tid & 63;
  const int row_w = wave & 1;
  const int pw    = (wave >> 1) & 1;
  const int coh   = wave >> 2;
  const int co_w  = co0 + coh*MT*16;
  const int y = r0 + row_w;
  const int lr = lane & 15, q = lane >> 4;
  const int ls = lane >> 2, lq = lane & 3;   // staging lane split

  // zero px-pad slots (px 0 and 129), both input buffers, once
  if (tid < 64) {
    int q16 = tid & 3, u = tid >> 2;
    int side = u & 1, r = (u >> 1) & 3, buf = u >> 3;
    short8 z = {0,0,0,0,0,0,0,0};
    *(short8*)(lds + buf*IB + (r*130 + (side ? 129 : 0))*32 + q16*8) = z;
  }
  // zero OOB halo rows once (both buffers); staging never writes them
  if (r0 == 0) {
    short8 z = {0,0,0,0,0,0,0,0};
    for (int i = tid; i < 2*520; i += 512) {
      int buf = i / 520, j = i % 520;
      *((short8*)(lds + buf*IB) + j) = z;                    // row 0
    }
  }
  if (r0 == 126) {
    short8 z = {0,0,0,0,0,0,0,0};
    for (int i = tid; i < 2*520; i += 512) {
      int buf = i / 520, j = i % 520;
      *((short8*)(lds + buf*IB + (SR-1)*130*32) + j) = z;    // row SR-1
    }
  }

  const size_t in_base = (size_t)b * HW * Ci;
  // input: 4 gload_lds per wave per chunk (32 segs = 4 rows x 8 px-segments)
  auto stage_i = [&](int buf, int ci0) {
    #pragma unroll
    for (int it = 0; it < 4; ++it) {
      int gi = wave*4 + it;
      int r = gi >> 3, seg = gi & 7;
      int yy = r0 + r - 1;
      if ((unsigned)yy < 128u)
        gload_lds16(xin + in_base + (size_t)(yy*128 + seg*16 + ls)*Ci + ci0 + lq*8,
                    lds + buf*IB + (r*130 + seg*16 + 1)*32);
    }
  };
  // weights: UW 1KB-units (16 co-rows x 32 ci each), strided over 8 waves
  auto stage_w = [&](int ci0) {
    for (int u = wave; u < UW; u += 8) {
      int t = u / (WCO/16), cb = u % (WCO/16);
      gload_lds16(wpk + ((size_t)(t*Co + co0 + cb*16 + ls))*Ci + ci0 + lq*8,
                  wlds + (t*WCO + cb*16)*32);
    }
  };

  f32x4 acc[MT][NT] = {};
  stage_i(0, 0);
  __syncthreads();                 // zeros visible + first input drained
  int cur = 0;
  for (int c = 0; c < NC; ++c) {
    const int ci0 = c*32;
    stage_w(ci0);                  // oldest in-flight after prev leftovers
    if (c+1 < NC) {
      stage_i(cur^1, ci0 + 32);    // newest: keeps flying under compute
      asm volatile("s_waitcnt vmcnt(4)" ::: "memory");
    } else {
      asm volatile("s_waitcnt vmcnt(0)" ::: "memory");
    }
    __builtin_amdgcn_s_barrier();  // raw: no auto vmcnt(0) drain
    __builtin_amdgcn_sched_barrier(0);
    const short* ib = lds + cur*IB;
    #pragma unroll
    for (int t = 0; t < 9; ++t) {
      const int dy = t/3, dx = t%3;
      short8 af[MT], bf[NT];
      #pragma unroll
      for (int mt = 0; mt < MT; ++mt)
        af[mt] = *(const short8*)(wlds + (t*WCO + coh*MT*16 + mt*16 + lr)*32 + q*8);
      #pragma unroll
      for (int nt = 0; nt < NT; ++nt)
        bf[nt] = *(const short8*)(ib + ((row_w+dy)*130 + pw*64 + nt*16 + lr + dx)*32 + q*8);
      #pragma unroll
      for (int mt = 0; mt < MT; ++mt)
        #pragma unroll
        for (int nt = 0; nt < NT; ++nt)
          acc[mt][nt] = __builtin_amdgcn_mfma_f32_16x16x32_bf16(
              af[mt], bf[nt], acc[mt][nt], 0, 0, 0);
    }
    __builtin_amdgcn_s_barrier();  // all waves done reading before overwrite
    cur ^= 1;
  }

  // epilogue: +bias, store, and accumulate GN partial stats
  float sg[NGW] = {}, ssg[NGW] = {};
  #pragma unroll
  for (int mt = 0; mt < MT; ++mt) {
    const int g = (mt*16) / CPG;
    #pragma unroll
    for (int nt = 0; nt < NT; ++nt) {
      int px = pw*64 + nt*16 + lr;
      int co = co_w + mt*16 + q*4;
      const float4 bv = *(const float4*)(bias + co);
      f32x4 v = acc[mt][nt];
      v[0] += bv.x; v[1] += bv.y; v[2] += bv.z; v[3] += bv.w;
      sg[g]  += v[0] + v[1] + v[2] + v[3];
      ssg[g] += v[0]*v[0] + v[1]*v[1] + v[2]*v[2] + v[3]*v[3];
      *(f32x4*)(out + ((size_t)(b*HW + y*128 + px))*Co + co) = v;
    }
  }
  const int bgbase = b*(Co/CPG) + co_w/CPG;
  #pragma unroll
  for (int g = 0; g < NGW; ++g) {
    float s = sg[g], ss = ssg[g];
    #pragma unroll
    for (int off = 32; off; off >>= 1) {
      s  += __shfl_xor(s, off);
      ss += __shfl_xor(ss, off);
    }
    if (lane == 0) {
      atomicAdd(&partS[bgbase + g], s);
      atomicAdd(&partSS[bgbase + g], ss);
    }
  }
}

// ---- GN finalize: mean / rsqrt(var) from atomic partials -------------------
__global__ void gn_final_k(const float* __restrict__ partS,
                           const float* __restrict__ partSS,
                           float* __restrict__ mv, int nbg, float inv_n)
{
  const int i = threadIdx.x;
  if (i < nbg) {
    float s = partS[i], ss = partSS[i];
    float mean = s*inv_n, var = ss*inv_n - mean*mean;
    mv[2*i] = mean; mv[2*i+1] = rsqrtf(var + 1e-5f);
  }
}

// ---- GN apply: normalize+affine+ReLU; emit bf16 (or fp32) NHWC -------------
template<int C, int CPG, bool BF16OUT>
__global__ __launch_bounds__(256) void gn_apply_k(const float* __restrict__ in,
    const float* __restrict__ mv, const float* __restrict__ gw,
    const float* __restrict__ gb, void* __restrict__ outp)
{
  constexpr int C4 = C/4;
  constexpr int G = C/CPG;
  const int i = blockIdx.x*256 + threadIdx.x;
  const int c4 = i & (C4-1);
  const int pxb = i >> __builtin_ctz(C4);
  const int b = pxb >> 14;
  const int c = c4*4;
  const int bg = b*G + c/CPG;
  const float mean = mv[2*bg], inv = mv[2*bg+1];
  float4 v = *((const float4*)in + i);
  const float4 w4 = *(const float4*)(gw + c);
  const float4 b4 = *(const float4*)(gb + c);
  float r0 = fmaxf((v.x-mean)*inv*w4.x + b4.x, 0.f);
  float r1 = fmaxf((v.y-mean)*inv*w4.y + b4.y, 0.f);
  float r2 = fmaxf((v.z-mean)*inv*w4.z + b4.z, 0.f);
  float r3 = fmaxf((v.w-mean)*inv*w4.w + b4.w, 0.f);
  if (BF16OUT) {
    uint2 o;
    o.x = ((unsigned)bfbits(r1) << 16) | bfbits(r0);
    o.y = ((unsigned)bfbits(r3) << 16) | bfbits(r2);
    *(uint2*)((__hip_bfloat16*)outp + (size_t)i*4) = o;
  } else {
    *((float4*)outp + i) = make_float4(r0,r1,r2,r3);
  }
}

// ---- pooling ---------------------------------------------------------------
__global__ __launch_bounds__(256) void pool_counts_k(
    const int* __restrict__ masks, float* __restrict__ counts)
{
  __shared__ int hist[KIDS];
  const int b = blockIdx.x;
  if (threadIdx.x < KIDS) hist[threadIdx.x] = 0;
  __syncthreads();
  for (int p = threadIdx.x; p < HW; p += 256) {
    const int m = masks[b*HW + p];
    if (m > 0) atomicAdd(&hist[m-1], 1);
  }
  __syncthreads();
  if (threadIdx.x < KIDS) counts[b*KIDS + threadIdx.x] = (float)hist[threadIdx.x];
}

__global__ __launch_bounds__(256) void pool_sums_k(const float* __restrict__ h3,
    const int* __restrict__ masks, float* __restrict__ sums)
{
  __shared__ float acc[KIDS*64];
  const int b = blockIdx.x >> 5, chunk = blockIdx.x & 31;
  const int tid = threadIdx.x;
  for (int j = tid; j < KIDS*64; j += 256) acc[j] = 0.f;
  __syncthreads();
  const int ch = tid & 63, pi = tid >> 6;
  const int p0 = chunk*512;
  for (int p = p0 + pi; p < p0 + 512; p += 4) {
    int m = masks[b*HW + p];
    if (m > 0) atomicAdd(&acc[(m-1)*64 + ch], h3[((size_t)(b*HW + p))*64 + ch]);
  }
  __syncthreads();
  for (int j = tid; j < KIDS*64; j += 256) atomicAdd(&sums[b*KIDS*64 + j], acc[j]);
}

// ---- heads: one wave per (b,k) ---------------------------------------------
__global__ __launch_bounds__(64) void heads_k(
    const float* __restrict__ sums, const float* __restrict__ counts,
    const float* __restrict__ wb, const float* __restrict__ bb,
    const float* __restrict__ wc, const float* __restrict__ bc,
    float* __restrict__ out)
{
  const int bk = blockIdx.x;
  const int c = threadIdx.x;
  const float pooled = sums[bk*64 + c] / (counts[bk] + 1e-6f);
  #pragma unroll
  for (int o = 0; o < 7; ++o) {
    float t = pooled * wb[o*64 + c];
    for (int off = 32; off > 0; off >>= 1) t += __shfl_down(t, off);
    if (c == 0) out[bk*7 + o] = t + bb[o];
  }
  float t = pooled * wc[c];
  for (int off = 32; off > 0; off >>= 1) t += __shfl_down(t, off);
  if (c == 0) out[BATCH*KIDS*7 + bk] = 1.f / (1.f + expf(-(t + bc[0])));
}

extern "C" void kernel_launch(void* const* d_in, const int* in_sizes, int n_in,
                              void* d_out, int out_size, void* d_ws, size_t ws_size,
                              hipStream_t stream)
{
  const float* x     = (const float*)d_in[0];
  const int*   masks = (const int*)  d_in[1];
  const float* w1 = (const float*)d_in[2];
  const float* b1 = (const float*)d_in[3];
  const float* g1w= (const float*)d_in[4];
  const float* g1b= (const float*)d_in[5];
  const float* w2 = (const float*)d_in[6];
  const float* b2 = (const float*)d_in[7];
  const float* g2w= (const float*)d_in[8];
  const float* g2b= (const float*)d_in[9];
  const float* w3 = (const float*)d_in[10];
  const float* b3 = (const float*)d_in[11];
  const float* g3w= (const float*)d_in[12];
  const float* g3b= (const float*)d_in[13];
  const float* wb = (const float*)d_in[14];
  const float* bb = (const float*)d_in[15];
  const float* wc = (const float*)d_in[16];
  const float* bc = (const float*)d_in[17];
  float* out = (float*)d_out;

  char* ws = (char*)d_ws;
  // region A [0,64MB): xb during conv1; then h1b(32) + h2b(16) + h3(16)
  __hip_bfloat16* xb  = (__hip_bfloat16*)ws;
  __hip_bfloat16* h1b = (__hip_bfloat16*)ws;
  __hip_bfloat16* h2b = (__hip_bfloat16*)(ws + (size_t)(32<<20));
  float*          h3  = (float*)         (ws + (size_t)(48<<20));
  // region B [64,128MB): c1(64); then c2(32)+c3(16)
  float* c1 = (float*)(ws + (size_t)(64<<20));
  float* c2 = c1;
  float* c3 = (float*)(ws + (size_t)(96<<20));
  // packed weights + small buffers at 128MB
  __hip_bfloat16* wp1 = (__hip_bfloat16*)(ws + (size_t)(128<<20));
  __hip_bfloat16* wp2 = wp1 + 9*256*512;
  __hip_bfloat16* wp3 = wp2 + 9*128*256;
  char* tail = (char*)(wp3 + 9*64*128);
  float* mv     = (float*)tail;                 // 64 floats
  float* partS  = mv + 64;                      // 64 (layer offs 0/32/48)
  float* partSS = partS + 64;                   // 64
  float* sums   = partSS + 64;                  // 5120
  float* counts = sums + 5120;                  // 80

  // zero atomic accumulators (partS, partSS, sums are contiguous: 5248 floats)
  zero_k<<<21, 256, 0, stream>>>(partS, 64 + 64 + 5120);

  x_to_nhwc_k<<<16384, 256, 0, stream>>>(x, xb);
  pack_w_k<256,512><<<4608, 256, 0, stream>>>(w1, wp1);
  pack_w_k<128,256><<<1152, 256, 0, stream>>>(w2, wp2);
  pack_w_k< 64,128><<< 288, 256, 0, stream>>>(w3, wp3);

  // layer 1: 512 -> 256, GN(8 groups, cpg 32). 128co/block, 512 blocks
  conv_mfma_k<512,256,32,4><<<dim3(256,2), 512, 0, stream>>>(
      xb, wp1, b1, c1, partS, partSS);
  gn_final_k<<<1, 64, 0, stream>>>(partS, partSS, mv, 32, 1.f/(32.f*HW));
  gn_apply_k<256,32,true><<<16384, 256, 0, stream>>>(c1, mv, g1w, g1b, h1b);

  // layer 2: 256 -> 128, GN(4 groups, cpg 32). 128co/block, 256 blocks
  conv_mfma_k<256,128,32,4><<<dim3(256,1), 512, 0, stream>>>(
      h1b, wp2, b2, c2, partS + 32, partSS + 32);
  gn_final_k<<<1, 64, 0, stream>>>(partS + 32, partSS + 32, mv, 16, 1.f/(32.f*HW));
  gn_apply_k<128,32,true><<<8192, 256, 0, stream>>>(c2, mv, g2w, g2b, h2b);

  // layer 3: 128 -> 64, GN(4 groups, cpg 16); fp32 out. 64co/block (MT=2)
  conv_mfma_k<128,64,16,2><<<dim3(256,1), 512, 0, stream>>>(
      h2b, wp3, b3, c3, partS + 48, partSS + 48);
  gn_final_k<<<1, 64, 0, stream>>>(partS + 48, partSS + 48, mv, 16, 1.f/(16.f*HW));
  gn_apply_k<64,16,false><<<4096, 256, 0, stream>>>(c3, mv, g3w, g3b, h3);

  // pooling + heads
  pool_counts_k<<<BATCH, 256, 0, stream>>>(masks, counts);
  pool_sums_k<<<BATCH*32, 256, 0, stream>>>(h3, masks, sums);
  heads_k<<<BATCH*KIDS, 64, 0, stream>>>(sums, counts, wb, bb, wc, bc, out);
}